// Round 2
// baseline (742.506 us; speedup 1.0000x reference)
//
#include <hip/hip_runtime.h>
#include <math.h>

// B=16384, D=4096 (+3 tail features), H=128, E=64, K=8
#define DGL 4096
#define HGL 128
#define EGL 64
#define DELTA 5e-4f    // top8/9 gap threshold for fp32 recompute (split err sigma ~1.5e-5)

typedef short  short8 __attribute__((ext_vector_type(8)));
typedef float  f32x4  __attribute__((ext_vector_type(4)));

__device__ inline unsigned short bf16_rne(float x) {
    unsigned u = __float_as_uint(x);
    u += 0x7FFFu + ((u >> 16) & 1u);
    return (unsigned short)(u >> 16);
}
// truncation-hi + RNE-lo split: hi+lo represents x to ~2^-17 rel
__device__ inline void split2(float x, short& hi, short& lo) {
    unsigned u = __float_as_uint(x);
    hi = (short)(u >> 16);
    float hif = __uint_as_float(u & 0xFFFF0000u);
    lo = (short)bf16_rne(x - hif);
}
__device__ inline void split8(const float* f, short8& hi, short8& lo) {
#pragma unroll
    for (int j = 0; j < 8; ++j) { short h, l2; split2(f[j], h, l2); hi[j] = h; lo[j] = l2; }
}

// ---- pack W1[0:4096] into bf16 hi/lo MFMA B-fragments (layout verified round 2/3) ----
// wsB1[kci*8192 + ((nt*2+h)*64 + lane)*8 + j]; lane l holds B[k=kci*32+(l>>4)*8+j][n=nt*16+(l&15)]
__global__ void pack_w1(const float* __restrict__ W1, unsigned short* __restrict__ wsB1) {
    const int b = blockIdx.x;              // 1024 = 128 kci * 8 nt
    const int kci = b >> 3, nt = b & 7;
    const int l = threadIdx.x, quad = l >> 4, l15 = l & 15;
    short8 vh, vl;
#pragma unroll
    for (int j = 0; j < 8; ++j) {
        const int k = kci * 32 + quad * 8 + j;
        short h, lo; split2(W1[(size_t)k * HGL + nt * 16 + l15], h, lo);
        vh[j] = h; vl[j] = lo;
    }
    *(short8*)(wsB1 + (size_t)kci * 8192 + ((nt * 2 + 0) * 64 + l) * 8) = vh;
    *(short8*)(wsB1 + (size_t)kci * 8192 + ((nt * 2 + 1) * 64 + l) * 8) = vl;
}

// ---- pack W2 (128x64) frags; also zero the refine-list counter ----
__global__ void pack_w2(const float* __restrict__ W2, unsigned short* __restrict__ wsB2,
                        int* __restrict__ gcount) {
    if (blockIdx.x == 0 && threadIdx.x == 0) *gcount = 0;
    const int b = blockIdx.x;              // 16 = 4 kc2 * 4 nt
    const int kc2 = b >> 2, nt = b & 3;
    const int l = threadIdx.x, quad = l >> 4, l15 = l & 15;
    short8 vh, vl;
#pragma unroll
    for (int j = 0; j < 8; ++j) {
        const int k = kc2 * 32 + quad * 8 + j;
        short h, lo; split2(W2[k * EGL + nt * 16 + l15], h, lo);
        vh[j] = h; vl[j] = lo;
    }
    *(short8*)(wsB2 + ((kc2 * 4 + nt) * 2 + 0) * 512 + l * 8) = vh;
    *(short8*)(wsB2 + ((kc2 * 4 + nt) * 2 + 1) * 512 + l * 8) = vl;
}

// ---- main: 512 threads = 8 waves, 32 rows/block, K split 8-way across waves ----
// Grid B/32=512 blocks x 8 waves = 16 waves/CU (50% occupancy) vs old 8 (25%).
// No barriers in the K-loop; two parallel 4-deep LDS reduction trees + epilogue.
__global__ __launch_bounds__(512, 4) void router_main(
    const float* __restrict__ r_pooled, const float* __restrict__ step_frac,
    const float* __restrict__ hn, const float* __restrict__ cf,
    const float* __restrict__ W1, const float* __restrict__ b1,
    const float* __restrict__ b2v,
    const unsigned short* __restrict__ wsB1, const unsigned short* __restrict__ wsB2,
    int* __restrict__ gcount, int* __restrict__ glist,
    float* __restrict__ out_w, float* __restrict__ out_l)
{
    __shared__ float hsum[32 * 132];   // reduced h (waves 0-3), [row][col] stride 132
    __shared__ float hsum2[32 * 132];  // reduced h (waves 4-7)
    __shared__ float ls[32 * 65];      // logits tile for topk
    __shared__ float wt[32 * 65];      // weights tile

    const int t = threadIdx.x;
    const int w = t >> 6, l = t & 63;
    const int quad = l >> 4, l15 = l & 15;
    const int row0 = blockIdx.x * 32;

    // this wave's K-range: 512 wide, kci_glob in [w*16, w*16+16)
    const float* aB0 = r_pooled + (size_t)(row0 + l15) * DGL + w * 512 + quad * 8;
    const float* aB1 = aB0 + (size_t)16 * DGL;

    f32x4 acc[2][8];
#pragma unroll
    for (int m = 0; m < 2; ++m)
#pragma unroll
        for (int nt = 0; nt < 8; ++nt) acc[m][nt] = (f32x4){0.f, 0.f, 0.f, 0.f};

    float4 a0[4];
    a0[0] = *(const float4*)(aB0);
    a0[1] = *(const float4*)(aB0 + 4);
    a0[2] = *(const float4*)(aB1);
    a0[3] = *(const float4*)(aB1 + 4);

    for (int kci = 0; kci < 16; ++kci) {
        const int kn = (kci + 1 < 16) ? (kci + 1) : 15;
        float4 a1[4];
        a1[0] = *(const float4*)(aB0 + kn * 32);
        a1[1] = *(const float4*)(aB0 + kn * 32 + 4);
        a1[2] = *(const float4*)(aB1 + kn * 32);
        a1[3] = *(const float4*)(aB1 + kn * 32 + 4);

        const unsigned short* bp = wsB1 + (size_t)(w * 16 + kci) * 8192 + l * 8;
        short8 b[16];
#pragma unroll
        for (int nt = 0; nt < 8; ++nt) {
            b[2 * nt]     = *(const short8*)(bp + (2 * nt) * 512);
            b[2 * nt + 1] = *(const short8*)(bp + (2 * nt + 1) * 512);
        }

        short8 ahi[2], alo[2];
#pragma unroll
        for (int m = 0; m < 2; ++m) {
            float fa[8];
#pragma unroll
            for (int j = 0; j < 4; ++j) { fa[j] = a0[2 * m][j]; fa[j + 4] = a0[2 * m + 1][j]; }
            split8(fa, ahi[m], alo[m]);
        }
#pragma unroll
        for (int m = 0; m < 2; ++m)
#pragma unroll
            for (int nt = 0; nt < 8; ++nt) {
                acc[m][nt] = __builtin_amdgcn_mfma_f32_16x16x32_bf16(ahi[m], b[2 * nt],     acc[m][nt], 0, 0, 0);
                acc[m][nt] = __builtin_amdgcn_mfma_f32_16x16x32_bf16(ahi[m], b[2 * nt + 1], acc[m][nt], 0, 0, 0);
                acc[m][nt] = __builtin_amdgcn_mfma_f32_16x16x32_bf16(alo[m], b[2 * nt],     acc[m][nt], 0, 0, 0);
            }
#pragma unroll
        for (int i = 0; i < 4; ++i) a0[i] = a1[i];
    }

    // ---- reduce the 8 K-partials: two parallel 4-deep sequential trees ----
    // C layout: row_local = m*16 + quad*4 + r, col = nt*16 + l15
    if (w == 0) {
#pragma unroll
        for (int m = 0; m < 2; ++m)
#pragma unroll
            for (int nt = 0; nt < 8; ++nt)
#pragma unroll
                for (int r = 0; r < 4; ++r)
                    hsum[(m * 16 + quad * 4 + r) * 132 + nt * 16 + l15] = acc[m][nt][r];
    }
    if (w == 4) {
#pragma unroll
        for (int m = 0; m < 2; ++m)
#pragma unroll
            for (int nt = 0; nt < 8; ++nt)
#pragma unroll
                for (int r = 0; r < 4; ++r)
                    hsum2[(m * 16 + quad * 4 + r) * 132 + nt * 16 + l15] = acc[m][nt][r];
    }
    __syncthreads();
#pragma unroll
    for (int wv = 1; wv < 4; ++wv) {
        if (w == wv) {
#pragma unroll
            for (int m = 0; m < 2; ++m)
#pragma unroll
                for (int nt = 0; nt < 8; ++nt)
#pragma unroll
                    for (int r = 0; r < 4; ++r)
                        hsum[(m * 16 + quad * 4 + r) * 132 + nt * 16 + l15] += acc[m][nt][r];
        }
        if (w == wv + 4) {
#pragma unroll
            for (int m = 0; m < 2; ++m)
#pragma unroll
                for (int nt = 0; nt < 8; ++nt)
#pragma unroll
                    for (int r = 0; r < 4; ++r)
                        hsum2[(m * 16 + quad * 4 + r) * 132 + nt * 16 + l15] += acc[m][nt][r];
        }
        __syncthreads();
    }

    // ---- epilogue: combine trees + tail features + bias + silu, into hsum ----
    {
        const float sf = step_frac[0];
#pragma unroll
        for (int j = 0; j < 8; ++j) {
            const int idx = j * 512 + t;      // 0..4095
            const int r = idx >> 7, c = idx & 127;
            float x = hsum[r * 132 + c] + hsum2[r * 132 + c];
            x += sf * W1[(size_t)4096 * HGL + c]
               + hn[row0 + r] * W1[(size_t)4097 * HGL + c]
               + cf[row0 + r] * W1[(size_t)4098 * HGL + c] + b1[c];
            hsum[r * 132 + c] = x / (1.0f + expf(-x));
        }
    }
    __syncthreads();

    // ---- GEMM2 via MFMA: each of the 8 waves does one 16-row x 16-col quadrant ----
    const int mt2 = w >> 2, nt2 = w & 3;
    f32x4 acc2 = (f32x4){0.f, 0.f, 0.f, 0.f};
#pragma unroll
    for (int kc2 = 0; kc2 < 4; ++kc2) {
        const float4 va = *(const float4*)&hsum[(mt2 * 16 + l15) * 132 + kc2 * 32 + quad * 8];
        const float4 vb = *(const float4*)&hsum[(mt2 * 16 + l15) * 132 + kc2 * 32 + quad * 8 + 4];
        float fa[8];
#pragma unroll
        for (int j = 0; j < 4; ++j) { fa[j] = ((const float*)&va)[j]; fa[j + 4] = ((const float*)&vb)[j]; }
        short8 h2, lo2;
        split8(fa, h2, lo2);
        const short8 bh = *(const short8*)(wsB2 + ((kc2 * 4 + nt2) * 2 + 0) * 512 + l * 8);
        const short8 bl = *(const short8*)(wsB2 + ((kc2 * 4 + nt2) * 2 + 1) * 512 + l * 8);
        acc2 = __builtin_amdgcn_mfma_f32_16x16x32_bf16(h2,  bh, acc2, 0, 0, 0);
        acc2 = __builtin_amdgcn_mfma_f32_16x16x32_bf16(h2,  bl, acc2, 0, 0, 0);
        acc2 = __builtin_amdgcn_mfma_f32_16x16x32_bf16(lo2, bh, acc2, 0, 0, 0);
    }

    // ---- logits out + ls stage, zero wt ----
    {
        const int c = nt2 * 16 + l15;
        const float bv = b2v[c];
#pragma unroll
        for (int r = 0; r < 4; ++r) {
            const int lr = mt2 * 16 + quad * 4 + r;
            const float v = acc2[r] + bv;
            out_l[(size_t)(row0 + lr) * EGL + c] = v;
            ls[lr * 65 + c] = v;
        }
    }
    for (int i = t; i < 32 * 65; i += 512) wt[i] = 0.0f;
    __syncthreads();

    // ---- top-8 (+9th for gap), softmax, scatter, flag near-ties ----
    if (t < 32) {
        float vals[9]; int idxs[9];
#pragma unroll
        for (int i = 0; i < 9; ++i) { vals[i] = -INFINITY; idxs[i] = 0; }
        for (int e = 0; e < EGL; ++e) {
            const float v = ls[t * 65 + e];
            if (v > vals[8]) {
                int p = 8;
                while (p > 0 && v > vals[p - 1]) { vals[p] = vals[p - 1]; idxs[p] = idxs[p - 1]; --p; }
                vals[p] = v; idxs[p] = e;
            }
        }
        const float mx = vals[0];
        float wgt[8], ssum = 0.0f;
#pragma unroll
        for (int i = 0; i < 8; ++i) { wgt[i] = expf(vals[i] - mx); ssum += wgt[i]; }
        const float inv = 1.0f / ssum;
#pragma unroll
        for (int i = 0; i < 8; ++i) wt[t * 65 + idxs[i]] = wgt[i] * inv;
        if (vals[7] - vals[8] < DELTA) {
            int p = atomicAdd(gcount, 1);
            if (p < 16384) glist[p] = row0 + t;
        }
    }
    __syncthreads();

    for (int i = t; i < 32 * EGL; i += 512) {
        const int m = i >> 6, c = i & 63;
        out_w[(size_t)(row0 + m) * EGL + c] = wt[m * 65 + c];
    }
}

// ---- refine: fp32 recompute of listed rows ----
__global__ __launch_bounds__(512, 1) void refine_rows(
    const float* __restrict__ r_pooled, const float* __restrict__ step_frac,
    const float* __restrict__ hn, const float* __restrict__ cf,
    const float* __restrict__ W1, const float* __restrict__ b1,
    const float* __restrict__ W2, const float* __restrict__ b2,
    const int* __restrict__ gcount, const int* __restrict__ glist,
    float* __restrict__ out_w)
{
    __shared__ __align__(16) float als[DGL];
    __shared__ float part[4][128];
    __shared__ float hred[128];
    __shared__ float lb[64];
    __shared__ float wb[64];

    const int t = threadIdx.x;
    const int cnt = *gcount;
    const int c = t & 127, sl = t >> 7;

    for (int i = blockIdx.x; i < cnt; i += gridDim.x) {
        const int row = glist[i];
        __syncthreads();
        for (int j = t; j < DGL / 4; j += 512)
            *(float4*)&als[j * 4] = *(const float4*)&r_pooled[(size_t)row * DGL + j * 4];
        __syncthreads();

        float pr = 0.0f;
        const float* ap = als + sl * 1024;
        const float* wp = W1 + (size_t)(sl * 1024) * HGL + c;
#pragma unroll 8
        for (int k = 0; k < 1024; ++k) pr = fmaf(ap[k], wp[(size_t)k * HGL], pr);
        part[sl][c] = pr;
        __syncthreads();

        if (t < 128) {
            const float sf = step_frac[0];
            float x = part[0][t] + part[1][t] + part[2][t] + part[3][t];
            x += sf * W1[(size_t)4096 * HGL + t] + hn[row] * W1[(size_t)4097 * HGL + t]
               + cf[row] * W1[(size_t)4098 * HGL + t] + b1[t];
            hred[t] = x / (1.0f + expf(-x));
        }
        __syncthreads();
        if (t < 64) {
            float a = b2[t];
            for (int k = 0; k < HGL; ++k) a = fmaf(hred[k], W2[k * EGL + t], a);
            lb[t] = a; wb[t] = 0.0f;
        }
        __syncthreads();
        if (t == 0) {
            float vals[8]; int idxs[8];
#pragma unroll
            for (int q = 0; q < 8; ++q) { vals[q] = -INFINITY; idxs[q] = 0; }
            for (int e = 0; e < EGL; ++e) {
                const float v = lb[e];
                if (v > vals[7]) {
                    int p = 7;
                    while (p > 0 && v > vals[p - 1]) { vals[p] = vals[p - 1]; idxs[p] = idxs[p - 1]; --p; }
                    vals[p] = v; idxs[p] = e;
                }
            }
            const float mx = vals[0];
            float wgt[8], ssum = 0.0f;
#pragma unroll
            for (int q = 0; q < 8; ++q) { wgt[q] = expf(vals[q] - mx); ssum += wgt[q]; }
            const float inv = 1.0f / ssum;
#pragma unroll
            for (int q = 0; q < 8; ++q) wb[idxs[q]] = wgt[q] * inv;
        }
        __syncthreads();
        if (t < 64) out_w[(size_t)row * EGL + t] = wb[t];
    }
}

extern "C" void kernel_launch(void* const* d_in, const int* in_sizes, int n_in,
                              void* d_out, int out_size, void* d_ws, size_t ws_size,
                              hipStream_t stream) {
    const float* r_pooled    = (const float*)d_in[0];
    const float* step_frac   = (const float*)d_in[1];
    const float* hidden_norm = (const float*)d_in[2];
    const float* confidence  = (const float*)d_in[3];
    const float* W1          = (const float*)d_in[4];
    const float* b1          = (const float*)d_in[5];
    const float* W2          = (const float*)d_in[6];
    const float* b2          = (const float*)d_in[7];

    const int B = in_sizes[2];
    float* out_w = (float*)d_out;
    float* out_l = out_w + (size_t)B * EGL;

    unsigned short* wsB1 = (unsigned short*)d_ws;                    // 2 MB
    unsigned short* wsB2 = (unsigned short*)((char*)d_ws + 2097152); // 32 KB
    int* gcount = (int*)((char*)d_ws + 2129920);
    int* glist  = (int*)((char*)d_ws + 2129984);                     // 64 KB

    hipLaunchKernelGGL(pack_w1, dim3(1024), dim3(64), 0, stream, W1, wsB1);
    hipLaunchKernelGGL(pack_w2, dim3(16), dim3(64), 0, stream, W2, wsB2, gcount);
    hipLaunchKernelGGL(router_main, dim3(B / 32), dim3(512), 0, stream,
                       r_pooled, step_frac, hidden_norm, confidence,
                       W1, b1, b2, wsB1, wsB2, gcount, glist, out_w, out_l);
    hipLaunchKernelGGL(refine_rows, dim3(256), dim3(512), 0, stream,
                       r_pooled, step_frac, hidden_norm, confidence,
                       W1, b1, W2, b2, gcount, glist, out_w);
}

// Round 3
// 557.158 us; speedup vs baseline: 1.3327x; 1.3327x over previous
//
#include <hip/hip_runtime.h>
#include <math.h>

// B=16384, D=4096 (+3 tail features), H=128, E=64, K=8
#define DGL 4096
#define HGL 128
#define EGL 64
#define DELTA 5e-4f    // top8/9 gap threshold for fp32 recompute (split err sigma ~1.5e-5)

typedef short  short8 __attribute__((ext_vector_type(8)));
typedef float  f32x4  __attribute__((ext_vector_type(4)));

__device__ inline unsigned short bf16_rne(float x) {
    unsigned u = __float_as_uint(x);
    u += 0x7FFFu + ((u >> 16) & 1u);
    return (unsigned short)(u >> 16);
}
// truncation-hi + RNE-lo split: hi+lo represents x to ~2^-17 rel
__device__ inline void split2(float x, short& hi, short& lo) {
    unsigned u = __float_as_uint(x);
    hi = (short)(u >> 16);
    float hif = __uint_as_float(u & 0xFFFF0000u);
    lo = (short)bf16_rne(x - hif);
}
__device__ inline void split8(const float* f, short8& hi, short8& lo) {
#pragma unroll
    for (int j = 0; j < 8; ++j) { short h, l2; split2(f[j], h, l2); hi[j] = h; lo[j] = l2; }
}

// ---- pack W1[0:4096] into bf16 hi/lo MFMA B-fragments (layout verified round 2/3) ----
// wsB1[kci*8192 + ((nt*2+h)*64 + lane)*8 + j]; lane l holds B[k=kci*32+(l>>4)*8+j][n=nt*16+(l&15)]
__global__ void pack_w1(const float* __restrict__ W1, unsigned short* __restrict__ wsB1) {
    const int b = blockIdx.x;              // 1024 = 128 kci * 8 nt
    const int kci = b >> 3, nt = b & 7;
    const int l = threadIdx.x, quad = l >> 4, l15 = l & 15;
    short8 vh, vl;
#pragma unroll
    for (int j = 0; j < 8; ++j) {
        const int k = kci * 32 + quad * 8 + j;
        short h, lo; split2(W1[(size_t)k * HGL + nt * 16 + l15], h, lo);
        vh[j] = h; vl[j] = lo;
    }
    *(short8*)(wsB1 + (size_t)kci * 8192 + ((nt * 2 + 0) * 64 + l) * 8) = vh;
    *(short8*)(wsB1 + (size_t)kci * 8192 + ((nt * 2 + 1) * 64 + l) * 8) = vl;
}

// ---- pack W2 (128x64) frags; also zero the refine-list counter ----
__global__ void pack_w2(const float* __restrict__ W2, unsigned short* __restrict__ wsB2,
                        int* __restrict__ gcount) {
    if (blockIdx.x == 0 && threadIdx.x == 0) *gcount = 0;
    const int b = blockIdx.x;              // 16 = 4 kc2 * 4 nt
    const int kc2 = b >> 2, nt = b & 3;
    const int l = threadIdx.x, quad = l >> 4, l15 = l & 15;
    short8 vh, vl;
#pragma unroll
    for (int j = 0; j < 8; ++j) {
        const int k = kc2 * 32 + quad * 8 + j;
        short h, lo; split2(W2[k * EGL + nt * 16 + l15], h, lo);
        vh[j] = h; vl[j] = lo;
    }
    *(short8*)(wsB2 + ((kc2 * 4 + nt) * 2 + 0) * 512 + l * 8) = vh;
    *(short8*)(wsB2 + ((kc2 * 4 + nt) * 2 + 1) * 512 + l * 8) = vl;
}

// ---- main: 512 threads = 8 waves, 32 rows/block, K split 8-way across waves ----
// __launch_bounds__ 2nd arg is min-BLOCKS-per-CU on this compiler (round-2 evidence:
// (512,4) forced VGPR=64 = 2048/32waves -> catastrophic spill, WRITE_SIZE 551MB).
// (512,2) -> VGPR cap 128. Loop restructured to ~124 live regs:
//   - A prefetch reuses a0 regs (split first, then load kci+1 into same regs)
//   - B fragments software-pipelined 2-deep (16 regs) instead of all 16 (64 regs)
__global__ __launch_bounds__(512, 2) void router_main(
    const float* __restrict__ r_pooled, const float* __restrict__ step_frac,
    const float* __restrict__ hn, const float* __restrict__ cf,
    const float* __restrict__ W1, const float* __restrict__ b1,
    const float* __restrict__ b2v,
    const unsigned short* __restrict__ wsB1, const unsigned short* __restrict__ wsB2,
    int* __restrict__ gcount, int* __restrict__ glist,
    float* __restrict__ out_w, float* __restrict__ out_l)
{
    __shared__ float hsum[32 * 132];   // reduced h (waves 0-3), [row][col] stride 132
    __shared__ float hsum2[32 * 132];  // reduced h (waves 4-7)
    __shared__ float ls[32 * 65];      // logits tile for topk
    __shared__ float wt[32 * 65];      // weights tile

    const int t = threadIdx.x;
    const int w = t >> 6, l = t & 63;
    const int quad = l >> 4, l15 = l & 15;
    const int row0 = blockIdx.x * 32;

    // this wave's K-range: 512 wide, kci_glob in [w*16, w*16+16)
    const float* aB0 = r_pooled + (size_t)(row0 + l15) * DGL + w * 512 + quad * 8;
    const float* aB1 = aB0 + (size_t)16 * DGL;

    f32x4 acc[2][8];
#pragma unroll
    for (int m = 0; m < 2; ++m)
#pragma unroll
        for (int nt = 0; nt < 8; ++nt) acc[m][nt] = (f32x4){0.f, 0.f, 0.f, 0.f};

    float4 a0[4];
    a0[0] = *(const float4*)(aB0);
    a0[1] = *(const float4*)(aB0 + 4);
    a0[2] = *(const float4*)(aB1);
    a0[3] = *(const float4*)(aB1 + 4);

    for (int kci = 0; kci < 16; ++kci) {
        // split current A tile into MFMA fragments (a0 dead afterwards)
        short8 ahi[2], alo[2];
#pragma unroll
        for (int m = 0; m < 2; ++m) {
            float fa[8];
#pragma unroll
            for (int j = 0; j < 4; ++j) { fa[j] = a0[2 * m][j]; fa[j + 4] = a0[2 * m + 1][j]; }
            split8(fa, ahi[m], alo[m]);
        }
        // prefetch next A tile into the SAME registers (latency hidden under MFMAs)
        if (kci + 1 < 16) {
            const int kn = kci + 1;
            a0[0] = *(const float4*)(aB0 + kn * 32);
            a0[1] = *(const float4*)(aB0 + kn * 32 + 4);
            a0[2] = *(const float4*)(aB1 + kn * 32);
            a0[3] = *(const float4*)(aB1 + kn * 32 + 4);
        }

        const unsigned short* bp = wsB1 + (size_t)(w * 16 + kci) * 8192 + l * 8;
        // B pipeline: 2-deep (one nt-pair in flight)
        short8 bh = *(const short8*)(bp + 0 * 512);
        short8 bl = *(const short8*)(bp + 1 * 512);
#pragma unroll
        for (int nt = 0; nt < 8; ++nt) {
            short8 bhn, bln;
            if (nt < 7) {
                bhn = *(const short8*)(bp + (2 * nt + 2) * 512);
                bln = *(const short8*)(bp + (2 * nt + 3) * 512);
            }
            acc[0][nt] = __builtin_amdgcn_mfma_f32_16x16x32_bf16(ahi[0], bh, acc[0][nt], 0, 0, 0);
            acc[0][nt] = __builtin_amdgcn_mfma_f32_16x16x32_bf16(ahi[0], bl, acc[0][nt], 0, 0, 0);
            acc[0][nt] = __builtin_amdgcn_mfma_f32_16x16x32_bf16(alo[0], bh, acc[0][nt], 0, 0, 0);
            acc[1][nt] = __builtin_amdgcn_mfma_f32_16x16x32_bf16(ahi[1], bh, acc[1][nt], 0, 0, 0);
            acc[1][nt] = __builtin_amdgcn_mfma_f32_16x16x32_bf16(ahi[1], bl, acc[1][nt], 0, 0, 0);
            acc[1][nt] = __builtin_amdgcn_mfma_f32_16x16x32_bf16(alo[1], bh, acc[1][nt], 0, 0, 0);
            bh = bhn; bl = bln;
        }
    }

    // ---- reduce the 8 K-partials: two parallel 4-deep sequential trees ----
    // C layout: row_local = m*16 + quad*4 + r, col = nt*16 + l15
    if (w == 0) {
#pragma unroll
        for (int m = 0; m < 2; ++m)
#pragma unroll
            for (int nt = 0; nt < 8; ++nt)
#pragma unroll
                for (int r = 0; r < 4; ++r)
                    hsum[(m * 16 + quad * 4 + r) * 132 + nt * 16 + l15] = acc[m][nt][r];
    }
    if (w == 4) {
#pragma unroll
        for (int m = 0; m < 2; ++m)
#pragma unroll
            for (int nt = 0; nt < 8; ++nt)
#pragma unroll
                for (int r = 0; r < 4; ++r)
                    hsum2[(m * 16 + quad * 4 + r) * 132 + nt * 16 + l15] = acc[m][nt][r];
    }
    __syncthreads();
#pragma unroll
    for (int wv = 1; wv < 4; ++wv) {
        if (w == wv) {
#pragma unroll
            for (int m = 0; m < 2; ++m)
#pragma unroll
                for (int nt = 0; nt < 8; ++nt)
#pragma unroll
                    for (int r = 0; r < 4; ++r)
                        hsum[(m * 16 + quad * 4 + r) * 132 + nt * 16 + l15] += acc[m][nt][r];
        }
        if (w == wv + 4) {
#pragma unroll
            for (int m = 0; m < 2; ++m)
#pragma unroll
                for (int nt = 0; nt < 8; ++nt)
#pragma unroll
                    for (int r = 0; r < 4; ++r)
                        hsum2[(m * 16 + quad * 4 + r) * 132 + nt * 16 + l15] += acc[m][nt][r];
        }
        __syncthreads();
    }

    // ---- epilogue: combine trees + tail features + bias + silu, into hsum ----
    {
        const float sf = step_frac[0];
#pragma unroll
        for (int j = 0; j < 8; ++j) {
            const int idx = j * 512 + t;      // 0..4095
            const int r = idx >> 7, c = idx & 127;
            float x = hsum[r * 132 + c] + hsum2[r * 132 + c];
            x += sf * W1[(size_t)4096 * HGL + c]
               + hn[row0 + r] * W1[(size_t)4097 * HGL + c]
               + cf[row0 + r] * W1[(size_t)4098 * HGL + c] + b1[c];
            hsum[r * 132 + c] = x / (1.0f + expf(-x));
        }
    }
    __syncthreads();

    // ---- GEMM2 via MFMA: each of the 8 waves does one 16-row x 16-col quadrant ----
    const int mt2 = w >> 2, nt2 = w & 3;
    f32x4 acc2 = (f32x4){0.f, 0.f, 0.f, 0.f};
#pragma unroll
    for (int kc2 = 0; kc2 < 4; ++kc2) {
        const float4 va = *(const float4*)&hsum[(mt2 * 16 + l15) * 132 + kc2 * 32 + quad * 8];
        const float4 vb = *(const float4*)&hsum[(mt2 * 16 + l15) * 132 + kc2 * 32 + quad * 8 + 4];
        float fa[8];
#pragma unroll
        for (int j = 0; j < 4; ++j) { fa[j] = ((const float*)&va)[j]; fa[j + 4] = ((const float*)&vb)[j]; }
        short8 h2, lo2;
        split8(fa, h2, lo2);
        const short8 bh = *(const short8*)(wsB2 + ((kc2 * 4 + nt2) * 2 + 0) * 512 + l * 8);
        const short8 bl = *(const short8*)(wsB2 + ((kc2 * 4 + nt2) * 2 + 1) * 512 + l * 8);
        acc2 = __builtin_amdgcn_mfma_f32_16x16x32_bf16(h2,  bh, acc2, 0, 0, 0);
        acc2 = __builtin_amdgcn_mfma_f32_16x16x32_bf16(h2,  bl, acc2, 0, 0, 0);
        acc2 = __builtin_amdgcn_mfma_f32_16x16x32_bf16(lo2, bh, acc2, 0, 0, 0);
    }

    // ---- logits out + ls stage, zero wt ----
    {
        const int c = nt2 * 16 + l15;
        const float bv = b2v[c];
#pragma unroll
        for (int r = 0; r < 4; ++r) {
            const int lr = mt2 * 16 + quad * 4 + r;
            const float v = acc2[r] + bv;
            out_l[(size_t)(row0 + lr) * EGL + c] = v;
            ls[lr * 65 + c] = v;
        }
    }
    for (int i = t; i < 32 * 65; i += 512) wt[i] = 0.0f;
    __syncthreads();

    // ---- top-8 (+9th for gap), softmax, scatter, flag near-ties ----
    if (t < 32) {
        float vals[9]; int idxs[9];
#pragma unroll
        for (int i = 0; i < 9; ++i) { vals[i] = -INFINITY; idxs[i] = 0; }
        for (int e = 0; e < EGL; ++e) {
            const float v = ls[t * 65 + e];
            if (v > vals[8]) {
                int p = 8;
                while (p > 0 && v > vals[p - 1]) { vals[p] = vals[p - 1]; idxs[p] = idxs[p - 1]; --p; }
                vals[p] = v; idxs[p] = e;
            }
        }
        const float mx = vals[0];
        float wgt[8], ssum = 0.0f;
#pragma unroll
        for (int i = 0; i < 8; ++i) { wgt[i] = expf(vals[i] - mx); ssum += wgt[i]; }
        const float inv = 1.0f / ssum;
#pragma unroll
        for (int i = 0; i < 8; ++i) wt[t * 65 + idxs[i]] = wgt[i] * inv;
        if (vals[7] - vals[8] < DELTA) {
            int p = atomicAdd(gcount, 1);
            if (p < 16384) glist[p] = row0 + t;
        }
    }
    __syncthreads();

    for (int i = t; i < 32 * EGL; i += 512) {
        const int m = i >> 6, c = i & 63;
        out_w[(size_t)(row0 + m) * EGL + c] = wt[m * 65 + c];
    }
}

// ---- refine: fp32 recompute of listed rows ----
__global__ __launch_bounds__(512, 1) void refine_rows(
    const float* __restrict__ r_pooled, const float* __restrict__ step_frac,
    const float* __restrict__ hn, const float* __restrict__ cf,
    const float* __restrict__ W1, const float* __restrict__ b1,
    const float* __restrict__ W2, const float* __restrict__ b2,
    const int* __restrict__ gcount, const int* __restrict__ glist,
    float* __restrict__ out_w)
{
    __shared__ __align__(16) float als[DGL];
    __shared__ float part[4][128];
    __shared__ float hred[128];
    __shared__ float lb[64];
    __shared__ float wb[64];

    const int t = threadIdx.x;
    const int cnt = *gcount;
    const int c = t & 127, sl = t >> 7;

    for (int i = blockIdx.x; i < cnt; i += gridDim.x) {
        const int row = glist[i];
        __syncthreads();
        for (int j = t; j < DGL / 4; j += 512)
            *(float4*)&als[j * 4] = *(const float4*)&r_pooled[(size_t)row * DGL + j * 4];
        __syncthreads();

        float pr = 0.0f;
        const float* ap = als + sl * 1024;
        const float* wp = W1 + (size_t)(sl * 1024) * HGL + c;
#pragma unroll 8
        for (int k = 0; k < 1024; ++k) pr = fmaf(ap[k], wp[(size_t)k * HGL], pr);
        part[sl][c] = pr;
        __syncthreads();

        if (t < 128) {
            const float sf = step_frac[0];
            float x = part[0][t] + part[1][t] + part[2][t] + part[3][t];
            x += sf * W1[(size_t)4096 * HGL + t] + hn[row] * W1[(size_t)4097 * HGL + t]
               + cf[row] * W1[(size_t)4098 * HGL + t] + b1[t];
            hred[t] = x / (1.0f + expf(-x));
        }
        __syncthreads();
        if (t < 64) {
            float a = b2[t];
            for (int k = 0; k < HGL; ++k) a = fmaf(hred[k], W2[k * EGL + t], a);
            lb[t] = a; wb[t] = 0.0f;
        }
        __syncthreads();
        if (t == 0) {
            float vals[8]; int idxs[8];
#pragma unroll
            for (int q = 0; q < 8; ++q) { vals[q] = -INFINITY; idxs[q] = 0; }
            for (int e = 0; e < EGL; ++e) {
                const float v = lb[e];
                if (v > vals[7]) {
                    int p = 7;
                    while (p > 0 && v > vals[p - 1]) { vals[p] = vals[p - 1]; idxs[p] = idxs[p - 1]; --p; }
                    vals[p] = v; idxs[p] = e;
                }
            }
            const float mx = vals[0];
            float wgt[8], ssum = 0.0f;
#pragma unroll
            for (int q = 0; q < 8; ++q) { wgt[q] = expf(vals[q] - mx); ssum += wgt[q]; }
            const float inv = 1.0f / ssum;
#pragma unroll
            for (int q = 0; q < 8; ++q) wb[idxs[q]] = wgt[q] * inv;
        }
        __syncthreads();
        if (t < 64) out_w[(size_t)row * EGL + t] = wb[t];
    }
}

extern "C" void kernel_launch(void* const* d_in, const int* in_sizes, int n_in,
                              void* d_out, int out_size, void* d_ws, size_t ws_size,
                              hipStream_t stream) {
    const float* r_pooled    = (const float*)d_in[0];
    const float* step_frac   = (const float*)d_in[1];
    const float* hidden_norm = (const float*)d_in[2];
    const float* confidence  = (const float*)d_in[3];
    const float* W1          = (const float*)d_in[4];
    const float* b1          = (const float*)d_in[5];
    const float* W2          = (const float*)d_in[6];
    const float* b2          = (const float*)d_in[7];

    const int B = in_sizes[2];
    float* out_w = (float*)d_out;
    float* out_l = out_w + (size_t)B * EGL;

    unsigned short* wsB1 = (unsigned short*)d_ws;                    // 2 MB
    unsigned short* wsB2 = (unsigned short*)((char*)d_ws + 2097152); // 32 KB
    int* gcount = (int*)((char*)d_ws + 2129920);
    int* glist  = (int*)((char*)d_ws + 2129984);                     // 64 KB

    hipLaunchKernelGGL(pack_w1, dim3(1024), dim3(64), 0, stream, W1, wsB1);
    hipLaunchKernelGGL(pack_w2, dim3(16), dim3(64), 0, stream, W2, wsB2, gcount);
    hipLaunchKernelGGL(router_main, dim3(B / 32), dim3(512), 0, stream,
                       r_pooled, step_frac, hidden_norm, confidence,
                       W1, b1, b2, wsB1, wsB2, gcount, glist, out_w, out_l);
    hipLaunchKernelGGL(refine_rows, dim3(256), dim3(512), 0, stream,
                       r_pooled, step_frac, hidden_norm, confidence,
                       W1, b1, W2, b2, gcount, glist, out_w);
}